// Round 12
// baseline (192.798 us; speedup 1.0000x reference)
//
#include <hip/hip_runtime.h>
#include <math.h>

// Zero-padded symmetric weight tables: per sigma, layout is
// [8 zeros][w[R], ..., w[1], w[0], w[1], ..., w[R]][8 zeros]  (length 2R+17).
// Index m in [0, 2R] holds w[|m-R|] at table offset m+8. The pads absorb all
// out-of-range taps so the tap loops need no conditionals.
// Truncation (renormalized): sigma1 R4 / sigma2 R9 tails ~1e-6 (exact-ish);
// sigma4 R12 tail mass ~0.17% (largely cancels in cs/lc ratios);
// sigma8 R16 exact (also keeps the L1 path exact).
struct GW { float w[171]; };
constexpr int W05 = 0;    // sigma 0.5, R=2,  len 21
constexpr int W1  = 21;   // sigma 1,   R=4,  len 25
constexpr int W2  = 46;   // sigma 2,   R=9,  len 35
constexpr int W4  = 81;   // sigma 4,   R=12, len 41
constexpr int W8  = 122;  // sigma 8,   R=16, len 49

namespace {

constexpr float kC1 = 1e-4f;
constexpr float kC2 = 9e-4f;

// 512 threads/block, 32x32 output tile.
// LDS (64.5 KB -> 2 blocks/CU = 16 waves/CU):
//  sS/sD : [64][64] floats, float4-group g XOR'd by (row&7)   (16 KB each)
//  hb4   : [<=64 rows][32 slots] float4 (s,d,s2,d2), slot c^((c>>3)&3) (32 KB)
//  hbl   : L1 reuse of hb4: [64][32] floats, plain layout (8 KB).
// L1 fusion: blur is linear -> mean_ch blur(|d_ch|) = blur(sum_ch |d_ch|)/3.
//
// V-pass within-wave tap split: lanes l and l^32 (same wave) share one
// (column, 4-row group) slot; each reads only R+2 of the 2R+4 taps and
// accumulates partials for all 4 rows; one __shfl_xor(.,32) exchange (8
// floats) combines; lane keeps 2 rows (half A -> rows 0-1, B -> rows 2-3).
// All 512 threads busy; v-pass LDS reads per thread drop (2R+2) -> (R+2).

// Horizontal pass, rows trimmed to NROWS=32+2R (hrow h = halo row h+16-R).
// One entry per thread (NE = NROWS*8 <= 512).
template<int R, int WOFF>
__device__ __forceinline__ void hpass4(const GW& g, const float* __restrict__ sS,
                                       const float* __restrict__ sD,
                                       float4* __restrict__ hb, int t) {
  constexpr int NROWS = 32 + 2 * R;
  constexpr int NE = NROWS * 8;
  constexpr int QS = (16 - R) & ~3;
  constexpr int NG = ((19 + R - QS) >> 2) + 1;
  if (t >= NE) return;
  const int hrow = t >> 3;
  const int cg = t & 7;
  const int srow = hrow + (16 - R);
  const int rx = srow & 7;
  const int rowbase = srow << 6;
  const int g0 = cg + (QS >> 2);
  float a0[4] = {0.f, 0.f, 0.f, 0.f}, a1[4] = {0.f, 0.f, 0.f, 0.f};
  float a2[4] = {0.f, 0.f, 0.f, 0.f}, a3[4] = {0.f, 0.f, 0.f, 0.f};
#pragma unroll 2
  for (int j = 0; j < NG; ++j) {
    const int off = rowbase + (((g0 + j) ^ rx) << 2);
    const int wb = WOFF + 8 + QS - 16 + R + 4 * j;  // + u - o; pads absorb ends
    const float4 s4 = *reinterpret_cast<const float4*>(&sS[off]);
    const float4 d4 = *reinterpret_cast<const float4*>(&sD[off]);
    const float* sp = reinterpret_cast<const float*>(&s4);
    const float* dp = reinterpret_cast<const float*>(&d4);
#pragma unroll
    for (int u = 0; u < 4; ++u) {
      const float sv = sp[u], dv = dp[u];
      const float s2 = sv * sv, d2 = dv * dv;
#pragma unroll
      for (int o = 0; o < 4; ++o) {
        const float wk = g.w[wb + u - o];
        a0[o] += wk * sv; a1[o] += wk * dv;
        a2[o] += wk * s2; a3[o] += wk * d2;
      }
    }
  }
  const int rb = hrow << 5;
#pragma unroll
  for (int o = 0; o < 4; ++o) {
    const int c = (cg << 2) + o;
    hb[rb + (c ^ ((c >> 3) & 3))] = make_float4(a0[o], a1[o], a2[o], a3[o]);
  }
}

// V-pass partials: this lane's half of the tap range, all 4 rows of the slot.
// Weight window W[m], m = k-i+3 in [0, R+4]; compile-time-indexed selects
// avoid any runtime indexing of the byval struct (no scratch).
template<int R, int WOFF>
__device__ __forceinline__ void vpass_part(const GW& g, const float4* __restrict__ hb,
                                           int fc, int vr0, int half,
                                           float (&o0)[4], float (&o1)[4],
                                           float (&o2)[4], float (&o3)[4]) {
#pragma unroll
  for (int i = 0; i < 4; ++i) { o0[i] = o1[i] = o2[i] = o3[i] = 0.f; }
  float W[R + 5];
#pragma unroll
  for (int m = 0; m < R + 5; ++m)
    W[m] = half ? g.w[WOFF + 7 + R + m] : g.w[WOFF + 5 + m];
  const float4* __restrict__ hbp =
      hb + ((vr0 + (half ? (R + 2) : 0)) << 5) + fc;
#pragma unroll
  for (int k = 0; k < R + 2; ++k) {
    const float4 v = hbp[k << 5];
#pragma unroll
    for (int i = 0; i < 4; ++i) {
      const float wk = W[k - i + 3];
      o0[i] += wk * v.x; o1[i] += wk * v.y;
      o2[i] += wk * v.z; o3[i] += wk * v.w;
    }
  }
}

// Combine partner partials; lane keeps its 2 rows (A: i=0,1; B: i=2,3).
__device__ __forceinline__ void combine2(int half, const float (&o)[4],
                                         float (&keep)[2]) {
#pragma unroll
  for (int j = 0; j < 2; ++j) {
    const float send = half ? o[j] : o[j + 2];
    const float recv = __shfl_xor(send, 32, 64);
    keep[j] = (half ? o[j + 2] : o[j]) + recv;
  }
}

template<int R, int WOFF, int MULT, bool DOLM>
__device__ __forceinline__ void sweep4(const GW& g,
    const float* sS, const float* sD, float4* hb, int t, int fc, int vr0,
    int half, float (&PI)[2], float (&lM)[2]) {
  __syncthreads();                  // hb free, tile visible
  hpass4<R, WOFF>(g, sS, sD, hb, t);
  __syncthreads();
  float p0[4], p1[4], p2[4], p3[4];
  vpass_part<R, WOFF>(g, hb, fc, vr0, half, p0, p1, p2, p3);
  float os[2], od[2], os2[2], od2[2];
  combine2(half, p0, os);
  combine2(half, p1, od);
  combine2(half, p2, os2);
  combine2(half, p3, od2);
#pragma unroll
  for (int i = 0; i < 2; ++i) {
    const float vs = os2[i] - os[i] * os[i];   // Var(x+y)
    const float vd = od2[i] - od[i] * od[i];   // Var(x-y)
    const float cs = (0.5f * (vs - vd) + kC2) / (0.5f * (vs + vd) + kC2);
    float p = cs;
    if constexpr (MULT > 1) p *= cs;
    if constexpr (MULT > 2) p *= cs;
    PI[i] *= p;
    if constexpr (DOLM) {
      const float sa = os[i] * os[i], sb = od[i] * od[i];
      const float lc = (0.5f * (sa - sb) + kC1) / (0.5f * (sa + sb) + kC1);
      lM[i] = lc * lc * lc;
    }
  }
}

// L1 h-pass (sigma 8, R=16): blur of the pre-summed |d| tile in sD.
template<int R, int WOFF>
__device__ __forceinline__ void hpassL1(const GW& g, const float* __restrict__ sD,
                                        float* __restrict__ hbl, int t) {
  constexpr int QS = (16 - R) & ~3;
  constexpr int NG = ((19 + R - QS) >> 2) + 1;
  const int hrow = t >> 3;
  const int cg = t & 7;
  const int rx = hrow & 7;           // srow == hrow for R=16
  const int rowbase = hrow << 6;
  const int g0 = cg + (QS >> 2);
  float a0[4] = {0.f, 0.f, 0.f, 0.f};
#pragma unroll 2
  for (int j = 0; j < NG; ++j) {
    const int off = rowbase + (((g0 + j) ^ rx) << 2);
    const int wb = WOFF + 8 + QS - 16 + R + 4 * j;
    const float4 d4 = *reinterpret_cast<const float4*>(&sD[off]);
    const float* dp = reinterpret_cast<const float*>(&d4);
#pragma unroll
    for (int u = 0; u < 4; ++u) {
      const float av = dp[u];        // already >= 0 (sum of |d|)
#pragma unroll
      for (int o = 0; o < 4; ++o) a0[o] += g.w[wb + u - o] * av;
    }
  }
  *reinterpret_cast<float4*>(&hbl[(hrow << 5) + (cg << 2)]) =
      make_float4(a0[0], a0[1], a0[2], a0[3]);
}

// Fused L1 sweep: dump register-accumulated sum_ch |d| into sD (dead after the
// last hpass4), then one sigma-8 blur; same tap-split v-pass.
template<int R, int WOFF>
__device__ __forceinline__ void sweepL1_fused(const GW& g, float* sD, float* hbl,
                                              const float (&al1)[8], int t,
                                              int vc, int vr0, int half,
                                              float (&l1s)[2]) {
#pragma unroll
  for (int e = 0; e < 2; ++e) {
    const int gidx = t + (e << 9);
    const int ly = gidx >> 4, lg = gidx & 15;
    const int off = (ly << 6) + ((lg ^ (ly & 7)) << 2);
    *reinterpret_cast<float4*>(&sD[off]) =
        make_float4(al1[4 * e], al1[4 * e + 1], al1[4 * e + 2], al1[4 * e + 3]);
  }
  __syncthreads();
  hpassL1<R, WOFF>(g, sD, hbl, t);
  __syncthreads();
  float W[R + 5];
#pragma unroll
  for (int m = 0; m < R + 5; ++m)
    W[m] = half ? g.w[WOFF + 7 + R + m] : g.w[WOFF + 5 + m];
  float lp[4] = {0.f, 0.f, 0.f, 0.f};
  const float* __restrict__ hblp =
      hbl + ((vr0 + (half ? (R + 2) : 0)) << 5) + vc;
#pragma unroll
  for (int k = 0; k < R + 2; ++k) {
    const float vl = hblp[k << 5];
#pragma unroll
    for (int i = 0; i < 4; ++i) lp[i] += W[k - i + 3] * vl;
  }
  float keep[2];
  combine2(half, lp, keep);
#pragma unroll
  for (int j = 0; j < 2; ++j) l1s[j] += keep[j];
}

__device__ __forceinline__ void load_tile(const float* __restrict__ p1,
                                          const float* __restrict__ p2,
                                          float* __restrict__ sS, float* __restrict__ sD,
                                          float (&al1)[8], int t, int gx0, int gy0) {
#pragma unroll 1
  for (int e = 0; e < 2; ++e) {
    const int gidx = t + (e << 9);
    const int ly = gidx >> 4, lg = gidx & 15;
    const int gy = gy0 + ly;
    const int gx = gx0 + (lg << 2);
    float4 a = make_float4(0.f, 0.f, 0.f, 0.f);
    float4 b = make_float4(0.f, 0.f, 0.f, 0.f);
    if (gy >= 0 && gy < 512) {
      if (gx >= 0 && gx + 3 < 512) {
        a = *reinterpret_cast<const float4*>(&p1[(gy << 9) + gx]);
        b = *reinterpret_cast<const float4*>(&p2[(gy << 9) + gx]);
      } else {
        float* ap = reinterpret_cast<float*>(&a);
        float* bp = reinterpret_cast<float*>(&b);
#pragma unroll
        for (int u = 0; u < 4; ++u) {
          const int x = gx + u;
          if (x >= 0 && x < 512) { ap[u] = p1[(gy << 9) + x]; bp[u] = p2[(gy << 9) + x]; }
        }
      }
    }
    float4 s, d;
    s.x = a.x + b.x; s.y = a.y + b.y; s.z = a.z + b.z; s.w = a.w + b.w;
    d.x = a.x - b.x; d.y = a.y - b.y; d.z = a.z - b.z; d.w = a.w - b.w;
    al1[4 * e + 0] += fabsf(d.x); al1[4 * e + 1] += fabsf(d.y);
    al1[4 * e + 2] += fabsf(d.z); al1[4 * e + 3] += fabsf(d.w);
    const int off = (ly << 6) + ((lg ^ (ly & 7)) << 2);
    *reinterpret_cast<float4*>(&sS[off]) = s;
    *reinterpret_cast<float4*>(&sD[off]) = d;
  }
}

}  // namespace

extern "C" __global__ __launch_bounds__(512) void msssim_main(
    const float* __restrict__ img1, const float* __restrict__ img2,
    float* __restrict__ partial, GW g) {
  __shared__ __align__(16) float sS[4096];
  __shared__ __align__(16) float sD[4096];
  __shared__ __align__(16) float4 hb[2048];   // 32 KB; L1 aliases first 8 KB
  __shared__ float red[8];
  float* hbl = reinterpret_cast<float*>(hb);

  const int t = threadIdx.x;

  // XCD-contiguous swizzle: 2048 blocks / 8 XCDs -> XCD k owns batch image k.
  const int bid = (int)blockIdx.x + ((int)blockIdx.y << 4) + ((int)blockIdx.z << 8);
  const int swz = ((bid & 7) << 8) + (bid >> 3);
  const int bx = swz & 15, by = (swz >> 4) & 15, b = swz >> 8;

  const int gx0 = bx * 32 - 16;
  const int gy0 = by * 32 - 16;
  const int vc = t & 31;            // owned column
  const int half = (t >> 5) & 1;    // tap-half within the wave (lane l vs l^32)
  const int vr0 = (t >> 6) << 2;    // slot row base (4 rows, shared by pair)
  const int fc = vc ^ ((vc >> 3) & 3);

  float PI[2] = {1.f, 1.f};
  float lM[2] = {0.f, 0.f};
  float l1s[2] = {0.f, 0.f};
  float al1[8] = {0.f, 0.f, 0.f, 0.f, 0.f, 0.f, 0.f, 0.f};

  // Channel 0: cs(s0.5)^3 * cs(s1)^2
  {
    const float* p1 = img1 + (((size_t)b * 3 + 0) << 18);
    const float* p2 = img2 + (((size_t)b * 3 + 0) << 18);
    load_tile(p1, p2, sS, sD, al1, t, gx0, gy0);
    sweep4<2, W05, 3, false>(g, sS, sD, hb, t, fc, vr0, half, PI, lM);
    sweep4<4, W1, 2, false>(g, sS, sD, hb, t, fc, vr0, half, PI, lM);
  }
  // Channel 1: cs(s1)^1 * cs(s2)^3 * cs(s4)^1
  {
    const float* p1 = img1 + (((size_t)b * 3 + 1) << 18);
    const float* p2 = img2 + (((size_t)b * 3 + 1) << 18);
    load_tile(p1, p2, sS, sD, al1, t, gx0, gy0);
    sweep4<4, W1, 1, false>(g, sS, sD, hb, t, fc, vr0, half, PI, lM);
    sweep4<9, W2, 3, false>(g, sS, sD, hb, t, fc, vr0, half, PI, lM);
    sweep4<12, W4, 1, false>(g, sS, sD, hb, t, fc, vr0, half, PI, lM);
  }
  // Channel 2: cs(s4)^2 * cs(s8)^3 + lM(s8)
  {
    const float* p1 = img1 + (((size_t)b * 3 + 2) << 18);
    const float* p2 = img2 + (((size_t)b * 3 + 2) << 18);
    load_tile(p1, p2, sS, sD, al1, t, gx0, gy0);
    sweep4<12, W4, 2, false>(g, sS, sD, hb, t, fc, vr0, half, PI, lM);
    sweep4<16, W8, 3, true>(g, sS, sD, hb, t, fc, vr0, half, PI, lM);
  }
  // Fused L1: one sigma-8 blur of sum_ch |d| (linearity of conv).
  sweepL1_fused<16, W8>(g, sD, hbl, al1, t, vc, vr0, half, l1s);

  float s = 0.f;
#pragma unroll
  for (int i = 0; i < 2; ++i)
    s += 0.025f * (1.f - lM[i] * PI[i]) + 0.975f * (l1s[i] * (1.f / 3.f));

#pragma unroll
  for (int off = 32; off >= 1; off >>= 1) s += __shfl_down(s, off, 64);
  if ((t & 63) == 0) red[t >> 6] = s;
  __syncthreads();
  if (t == 0) {
    float tot = 0.f;
#pragma unroll
    for (int i = 0; i < 8; ++i) tot += red[i];
    partial[swz] = tot;
  }
}

extern "C" __global__ __launch_bounds__(256) void msssim_reduce(
    const float* __restrict__ partial, float* __restrict__ out, int n) {
  __shared__ float red[4];
  float s = 0.f;
  for (int i = threadIdx.x; i < n; i += 256) s += partial[i];
#pragma unroll
  for (int off = 32; off >= 1; off >>= 1) s += __shfl_down(s, off, 64);
  if ((threadIdx.x & 63) == 0) red[threadIdx.x >> 6] = s;
  __syncthreads();
  if (threadIdx.x == 0) {
    out[0] = (red[0] + red[1] + red[2] + red[3]) * (200.0f / 2097152.0f);
  }
}

extern "C" void kernel_launch(void* const* d_in, const int* in_sizes, int n_in,
                              void* d_out, int out_size, void* d_ws, size_t ws_size,
                              hipStream_t stream) {
  const float* img1 = (const float*)d_in[0];
  const float* img2 = (const float*)d_in[1];
  float* out = (float*)d_out;
  float* partial = (float*)d_ws;  // 2048 floats

  // Host-side padded weight tables (double-precision normalize over 2R+1 taps).
  GW g;
  {
    const double sig[5] = {0.5, 1.0, 2.0, 4.0, 8.0};
    const int R[5] = {2, 4, 9, 12, 16};
    const int off[5] = {W05, W1, W2, W4, W8};
    for (int i = 0; i < 5; ++i) {
      double tmp[17];
      double sum = 0.0;
      for (int k = 0; k <= R[i]; ++k) {
        tmp[k] = exp(-(double)(k * k) / (2.0 * sig[i] * sig[i]));
        sum += (k ? 2.0 : 1.0) * tmp[k];
      }
      const int len = 2 * R[i] + 17;
      for (int m = 0; m < len; ++m) {
        int d = m - 8 - R[i];
        if (d < 0) d = -d;
        g.w[off[i] + m] = (m >= 8 && m <= 8 + 2 * R[i]) ? (float)(tmp[d] / sum) : 0.0f;
      }
    }
  }

  dim3 grid(16, 16, 8);
  msssim_main<<<grid, dim3(512), 0, stream>>>(img1, img2, partial, g);
  msssim_reduce<<<1, dim3(256), 0, stream>>>(partial, out, 2048);
}

// Round 13
// 154.817 us; speedup vs baseline: 1.2453x; 1.2453x over previous
//
#include <hip/hip_runtime.h>
#include <hip/hip_fp16.h>
#include <math.h>

// Zero-padded symmetric weight tables (fp32, kernarg): per sigma,
// [8 zeros][w[R],...,w[1],w[0],w[1],...,w[R]][8 zeros]  (length 2R+17).
// Truncation (renormalized): sigma1 R4 / sigma2 R9 tails ~1e-6;
// sigma4 R12 tail ~0.17% (cancels in cs/lc ratios); sigma8 R16 exact.
struct GW { float w[171]; };
constexpr int W05 = 0;    // sigma 0.5, R=2
constexpr int W1  = 21;   // sigma 1,   R=4
constexpr int W2  = 46;   // sigma 2,   R=9
constexpr int W4  = 81;   // sigma 4,   R=12
constexpr int W8  = 122;  // sigma 8,   R=16

namespace {

constexpr float kC1 = 1e-4f;
constexpr float kC2 = 9e-4f;

// 512 threads/block, 32x32 output tile. LDS ~32.1 KB -> target 4 blocks/CU.
//  sT : [64 rows][64 cols] __half2 (s,d) per pixel, 16 KB.
//       phys half2 idx = (row<<6) + ((g ^ (row&7))<<2) + u   (g = 4-px group)
//  hb : [<=64 rows][32 cols] uint2 = 4xfp16 (s,d,s2,d2), 16 KB.
//       slot = c ^ (hrow&7)  (row-based XOR -> write conflicts spread;
//       v-pass reads recompute the same slot per row, bijective in vc).
//  L1 reuse of hb: Lin = 8 KB fp16 [64][64] |d|-sum tile, Lout = 4 KB fp16.
// Compute stays fp32; only LDS storage is fp16 (RN packing).

__device__ __forceinline__ unsigned int h2u(__half2 h) {
  union { __half2 h; unsigned int u; } cv; cv.h = h; return cv.u;
}
__device__ __forceinline__ __half2 u2h(unsigned int u) {
  union { __half2 h; unsigned int u; } cv; cv.u = u; return cv.h;
}

// Horizontal pass, rows trimmed to NROWS=32+2R. One entry per thread.
template<int R, int WOFF>
__device__ __forceinline__ void hpass4(const GW& g, const __half2* __restrict__ sT,
                                       uint2* __restrict__ hb, int t) {
  constexpr int NROWS = 32 + 2 * R;
  constexpr int NE = NROWS * 8;
  constexpr int QS = (16 - R) & ~3;
  constexpr int NG = ((19 + R - QS) >> 2) + 1;
  if (t >= NE) return;
  const int hrow = t >> 3;
  const int cg = t & 7;
  const int srow = hrow + (16 - R);
  const int rx = srow & 7;
  const int rowbase = srow << 6;
  const int g0 = cg + (QS >> 2);
  float a0[4] = {0.f, 0.f, 0.f, 0.f}, a1[4] = {0.f, 0.f, 0.f, 0.f};
  float a2[4] = {0.f, 0.f, 0.f, 0.f}, a3[4] = {0.f, 0.f, 0.f, 0.f};
#pragma unroll 2
  for (int j = 0; j < NG; ++j) {
    const int off = rowbase + (((g0 + j) ^ rx) << 2);
    const int wb = WOFF + 8 + QS - 16 + R + 4 * j;  // + u - o; pads absorb ends
    const float4 raw = *reinterpret_cast<const float4*>(&sT[off]);  // 4x half2
    const __half2* hp = reinterpret_cast<const __half2*>(&raw);
#pragma unroll
    for (int u = 0; u < 4; ++u) {
      const float2 sd = __half22float2(hp[u]);
      const float sv = sd.x, dv = sd.y;
      const float s2 = sv * sv, d2 = dv * dv;
#pragma unroll
      for (int o = 0; o < 4; ++o) {
        const float wk = g.w[wb + u - o];
        a0[o] += wk * sv; a1[o] += wk * dv;
        a2[o] += wk * s2; a3[o] += wk * d2;
      }
    }
  }
  const int rb = hrow << 5;
  const int hx = hrow & 7;
#pragma unroll
  for (int o = 0; o < 4; ++o) {
    const int c = (cg << 2) + o;
    hb[rb + (c ^ hx)] = make_uint2(h2u(__floats2half2_rn(a0[o], a1[o])),
                                   h2u(__floats2half2_rn(a2[o], a3[o])));
  }
}

// Vertical pass. Thread owns col vc = t&31, output rows vr0..vr0+1.
template<int R, int WOFF>
__device__ __forceinline__ void vpass4(const GW& g, const uint2* __restrict__ hb,
                                       int vc, int vr0,
                                       float (&o0)[2], float (&o1)[2],
                                       float (&o2)[2], float (&o3)[2]) {
#pragma unroll
  for (int i = 0; i < 2; ++i) { o0[i] = o1[i] = o2[i] = o3[i] = 0.f; }
#pragma unroll 4
  for (int jj = 0; jj < 2 * R + 2; ++jj) {
    const int r = vr0 + jj;
    const uint2 pk = hb[(r << 5) + (vc ^ (r & 7))];
    const float2 sd = __half22float2(u2h(pk.x));
    const float2 q  = __half22float2(u2h(pk.y));
    const int wb = WOFF + 8 + jj;   // weight index: wb - i; pads absorb ends
#pragma unroll
    for (int i = 0; i < 2; ++i) {
      const float wk = g.w[wb - i];
      o0[i] += wk * sd.x; o1[i] += wk * sd.y;
      o2[i] += wk * q.x;  o3[i] += wk * q.y;
    }
  }
}

template<int R, int WOFF, int MULT, bool DOLM>
__device__ __forceinline__ void sweep4(const GW& g,
    const __half2* sT, uint2* hb, int t, int vc, int vr0,
    float (&PI)[2], float (&lM)[2]) {
  __syncthreads();                  // hb free, tile visible
  hpass4<R, WOFF>(g, sT, hb, t);
  __syncthreads();
  float os[2], od[2], os2[2], od2[2];
  vpass4<R, WOFF>(g, hb, vc, vr0, os, od, os2, od2);
#pragma unroll
  for (int i = 0; i < 2; ++i) {
    const float vs = os2[i] - os[i] * os[i];   // Var(x+y)
    const float vd = od2[i] - od[i] * od[i];   // Var(x-y)
    const float cs = (0.5f * (vs - vd) + kC2) / (0.5f * (vs + vd) + kC2);
    float p = cs;
    if constexpr (MULT > 1) p *= cs;
    if constexpr (MULT > 2) p *= cs;
    PI[i] *= p;
    if constexpr (DOLM) {
      const float sa = os[i] * os[i], sb = od[i] * od[i];
      const float lc = (0.5f * (sa - sb) + kC1) / (0.5f * (sa + sb) + kC1);
      lM[i] = lc * lc * lc;
    }
  }
}

// Fused L1 (sigma 8, R=16): write reg-accumulated sum_ch |d| as fp16 into
// Lin (= hb low 8 KB, dead), h-pass into Lout (= hb next 4 KB), v-pass.
template<int R, int WOFF>
__device__ __forceinline__ void sweepL1_fused(const GW& g, uint2* hbmem,
                                              const float (&al1)[8], int t,
                                              int vc, int vr0, float (&l1s)[2]) {
  __half* Lin = reinterpret_cast<__half*>(hbmem);          // [64][64] halves
  __half* Lout = reinterpret_cast<__half*>(hbmem) + 4096;  // [64][32] halves
  __syncthreads();                  // final sweep's hb reads done
#pragma unroll
  for (int e = 0; e < 2; ++e) {
    const int gidx = t + (e << 9);
    const int ly = gidx >> 4, lg = gidx & 15;
    const int off = (ly << 6) + ((lg ^ (ly & 7)) << 2);  // half index
    *reinterpret_cast<uint2*>(&Lin[off]) =
        make_uint2(h2u(__floats2half2_rn(al1[4 * e], al1[4 * e + 1])),
                   h2u(__floats2half2_rn(al1[4 * e + 2], al1[4 * e + 3])));
  }
  __syncthreads();
  // h-pass (R=16: srow == hrow)
  {
    constexpr int QS = 0;
    constexpr int NG = ((19 + R) >> 2) + 1;
    const int hrow = t >> 3;
    const int cg = t & 7;
    const int rx = hrow & 7;
    const int rowbase = hrow << 6;
    const int g0 = cg;
    float a0[4] = {0.f, 0.f, 0.f, 0.f};
#pragma unroll 2
    for (int j = 0; j < NG; ++j) {
      const int off = rowbase + (((g0 + j) ^ rx) << 2);
      const int wb = WOFF + 8 + QS - 16 + R + 4 * j;
      const uint2 raw = *reinterpret_cast<const uint2*>(&Lin[off]);
      const float2 v01 = __half22float2(u2h(raw.x));
      const float2 v23 = __half22float2(u2h(raw.y));
      const float vv[4] = {v01.x, v01.y, v23.x, v23.y};
#pragma unroll
      for (int u = 0; u < 4; ++u) {
        const float av = vv[u];
#pragma unroll
        for (int o = 0; o < 4; ++o) a0[o] += g.w[wb + u - o] * av;
      }
    }
    *reinterpret_cast<uint2*>(&Lout[(hrow << 5) + (cg << 2)]) =
        make_uint2(h2u(__floats2half2_rn(a0[0], a0[1])),
                   h2u(__floats2half2_rn(a0[2], a0[3])));
  }
  __syncthreads();
#pragma unroll 4
  for (int jj = 0; jj < 2 * R + 2; ++jj) {
    const float vl = __half2float(Lout[((vr0 + jj) << 5) + vc]);
    const int wb = WOFF + 8 + jj;
#pragma unroll
    for (int i = 0; i < 2; ++i) l1s[i] += g.w[wb - i] * vl;
  }
}

__device__ __forceinline__ void load_tile(const float* __restrict__ p1,
                                          const float* __restrict__ p2,
                                          __half2* __restrict__ sT,
                                          float (&al1)[8], int t, int gx0, int gy0) {
#pragma unroll 1
  for (int e = 0; e < 2; ++e) {
    const int gidx = t + (e << 9);
    const int ly = gidx >> 4, lg = gidx & 15;
    const int gy = gy0 + ly;
    const int gx = gx0 + (lg << 2);
    float4 a = make_float4(0.f, 0.f, 0.f, 0.f);
    float4 b = make_float4(0.f, 0.f, 0.f, 0.f);
    if (gy >= 0 && gy < 512) {
      if (gx >= 0 && gx + 3 < 512) {
        a = *reinterpret_cast<const float4*>(&p1[(gy << 9) + gx]);
        b = *reinterpret_cast<const float4*>(&p2[(gy << 9) + gx]);
      } else {
        float* ap = reinterpret_cast<float*>(&a);
        float* bp = reinterpret_cast<float*>(&b);
#pragma unroll
        for (int u = 0; u < 4; ++u) {
          const int x = gx + u;
          if (x >= 0 && x < 512) { ap[u] = p1[(gy << 9) + x]; bp[u] = p2[(gy << 9) + x]; }
        }
      }
    }
    const float sv[4] = {a.x + b.x, a.y + b.y, a.z + b.z, a.w + b.w};
    const float dv[4] = {a.x - b.x, a.y - b.y, a.z - b.z, a.w - b.w};
    al1[4 * e + 0] += fabsf(dv[0]); al1[4 * e + 1] += fabsf(dv[1]);
    al1[4 * e + 2] += fabsf(dv[2]); al1[4 * e + 3] += fabsf(dv[3]);
    __half2 tmp[4];
#pragma unroll
    for (int u = 0; u < 4; ++u) tmp[u] = __floats2half2_rn(sv[u], dv[u]);
    const int off = (ly << 6) + ((lg ^ (ly & 7)) << 2);
    *reinterpret_cast<float4*>(&sT[off]) = *reinterpret_cast<float4*>(tmp);
  }
}

}  // namespace

extern "C" __global__ __launch_bounds__(512, 8) void msssim_main(
    const float* __restrict__ img1, const float* __restrict__ img2,
    float* __restrict__ partial, GW g) {
  __shared__ __align__(16) __half2 sT[4096];  // 16 KB (s,d)
  __shared__ __align__(16) uint2 hb[2048];    // 16 KB (s,d,s2,d2); L1 reuses
  __shared__ float red[8];

  const int t = threadIdx.x;

  // XCD-contiguous swizzle: 2048 blocks / 8 XCDs -> XCD k owns batch image k.
  const int bid = (int)blockIdx.x + ((int)blockIdx.y << 4) + ((int)blockIdx.z << 8);
  const int swz = ((bid & 7) << 8) + (bid >> 3);
  const int bx = swz & 15, by = (swz >> 4) & 15, b = swz >> 8;

  const int gx0 = bx * 32 - 16;
  const int gy0 = by * 32 - 16;
  const int vc = t & 31;          // owned column
  const int vr0 = (t >> 5) << 1;  // owned row base (2 consecutive rows)

  float PI[2] = {1.f, 1.f};
  float lM[2] = {0.f, 0.f};
  float l1s[2] = {0.f, 0.f};
  float al1[8] = {0.f, 0.f, 0.f, 0.f, 0.f, 0.f, 0.f, 0.f};

  // Channel 0: cs(s0.5)^3 * cs(s1)^2
  {
    const float* p1 = img1 + (((size_t)b * 3 + 0) << 18);
    const float* p2 = img2 + (((size_t)b * 3 + 0) << 18);
    load_tile(p1, p2, sT, al1, t, gx0, gy0);
    sweep4<2, W05, 3, false>(g, sT, hb, t, vc, vr0, PI, lM);
    sweep4<4, W1, 2, false>(g, sT, hb, t, vc, vr0, PI, lM);
  }
  // Channel 1: cs(s1)^1 * cs(s2)^3 * cs(s4)^1
  {
    const float* p1 = img1 + (((size_t)b * 3 + 1) << 18);
    const float* p2 = img2 + (((size_t)b * 3 + 1) << 18);
    __syncthreads();   // all hpass reads of sT done (mid-sweep barrier covers
                       // the last sweep's hpass; this covers its vpass only
                       // touching hb, so just order the tile overwrite)
    load_tile(p1, p2, sT, al1, t, gx0, gy0);
    sweep4<4, W1, 1, false>(g, sT, hb, t, vc, vr0, PI, lM);
    sweep4<9, W2, 3, false>(g, sT, hb, t, vc, vr0, PI, lM);
    sweep4<12, W4, 1, false>(g, sT, hb, t, vc, vr0, PI, lM);
  }
  // Channel 2: cs(s4)^2 * cs(s8)^3 + lM(s8)
  {
    const float* p1 = img1 + (((size_t)b * 3 + 2) << 18);
    const float* p2 = img2 + (((size_t)b * 3 + 2) << 18);
    __syncthreads();
    load_tile(p1, p2, sT, al1, t, gx0, gy0);
    sweep4<12, W4, 2, false>(g, sT, hb, t, vc, vr0, PI, lM);
    sweep4<16, W8, 3, true>(g, sT, hb, t, vc, vr0, PI, lM);
  }
  // Fused L1: one sigma-8 blur of sum_ch |d| (linearity of conv).
  sweepL1_fused<16, W8>(g, hb, al1, t, vc, vr0, l1s);

  float s = 0.f;
#pragma unroll
  for (int i = 0; i < 2; ++i)
    s += 0.025f * (1.f - lM[i] * PI[i]) + 0.975f * (l1s[i] * (1.f / 3.f));

#pragma unroll
  for (int off = 32; off >= 1; off >>= 1) s += __shfl_down(s, off, 64);
  if ((t & 63) == 0) red[t >> 6] = s;
  __syncthreads();
  if (t == 0) {
    float tot = 0.f;
#pragma unroll
    for (int i = 0; i < 8; ++i) tot += red[i];
    partial[swz] = tot;
  }
}

extern "C" __global__ __launch_bounds__(256) void msssim_reduce(
    const float* __restrict__ partial, float* __restrict__ out, int n) {
  __shared__ float red[4];
  float s = 0.f;
  for (int i = threadIdx.x; i < n; i += 256) s += partial[i];
#pragma unroll
  for (int off = 32; off >= 1; off >>= 1) s += __shfl_down(s, off, 64);
  if ((threadIdx.x & 63) == 0) red[threadIdx.x >> 6] = s;
  __syncthreads();
  if (threadIdx.x == 0) {
    out[0] = (red[0] + red[1] + red[2] + red[3]) * (200.0f / 2097152.0f);
  }
}

extern "C" void kernel_launch(void* const* d_in, const int* in_sizes, int n_in,
                              void* d_out, int out_size, void* d_ws, size_t ws_size,
                              hipStream_t stream) {
  const float* img1 = (const float*)d_in[0];
  const float* img2 = (const float*)d_in[1];
  float* out = (float*)d_out;
  float* partial = (float*)d_ws;  // 2048 floats

  // Host-side padded weight tables (double-precision normalize over 2R+1 taps).
  GW g;
  {
    const double sig[5] = {0.5, 1.0, 2.0, 4.0, 8.0};
    const int R[5] = {2, 4, 9, 12, 16};
    const int off[5] = {W05, W1, W2, W4, W8};
    for (int i = 0; i < 5; ++i) {
      double tmp[17];
      double sum = 0.0;
      for (int k = 0; k <= R[i]; ++k) {
        tmp[k] = exp(-(double)(k * k) / (2.0 * sig[i] * sig[i]));
        sum += (k ? 2.0 : 1.0) * tmp[k];
      }
      const int len = 2 * R[i] + 17;
      for (int m = 0; m < len; ++m) {
        int d = m - 8 - R[i];
        if (d < 0) d = -d;
        g.w[off[i] + m] = (m >= 8 && m <= 8 + 2 * R[i]) ? (float)(tmp[d] / sum) : 0.0f;
      }
    }
  }

  dim3 grid(16, 16, 8);
  msssim_main<<<grid, dim3(512), 0, stream>>>(img1, img2, partial, g);
  msssim_reduce<<<1, dim3(256), 0, stream>>>(partial, out, 2048);
}